// Round 3
// baseline (466.813 us; speedup 1.0000x reference)
//
#include <hip/hip_runtime.h>
#include <hip/hip_bf16.h>

// LSTM: I=32, H=64, O=8, B=4096, T=256, fused single kernel.
// Round 3: BR=8, grid=512, 2 blocks/CU. LDS traffic minimized:
//  - x K-tile fragments loaded straight from global (8 contiguous floats/lane),
//    prefetched 2 steps ahead; never staged in LDS.
//  - no gate redistribution: quads 0,1 activate 4 cells each (exec-masked).
//  - h double-buffered in LDS -> ONE barrier/step, implemented as raw
//    s_waitcnt lgkmcnt(0) + s_barrier so in-flight global prefetches are
//    NOT drained at the barrier (avoids the vmcnt(0) __syncthreads trap).
//  - bias folded into MFMA acc init (per-lane constant per gate).

#define T_LEN 256
#define I_SZ  32
#define H_SZ  64
#define O_SZ  8
#define BR    8
#define HS    72   // h row stride in shorts (= 36 dwords; 2-way banks on b128)

typedef __attribute__((ext_vector_type(8))) short short8;
typedef __attribute__((ext_vector_type(4))) float f32x4;

static __device__ __forceinline__ short f2bf(float f) {
    union { __hip_bfloat16 b; short s; } u;
    u.b = __float2bfloat16(f);
    return u.s;
}
static __device__ __forceinline__ float sigf(float x) {
    return __builtin_amdgcn_rcpf(1.0f + __expf(-x));
}
// tanh(x) = 1 - 2/(1+e^{2x}); saturates correctly via inf/0 at extremes.
static __device__ __forceinline__ float tanh_fast(float x) {
    return 1.0f - 2.0f * __builtin_amdgcn_rcpf(1.0f + __expf(2.0f * x));
}

// Barrier with LDS drain only: lets global prefetch loads stay in flight.
#define BAR() do { \
    asm volatile("s_waitcnt lgkmcnt(0)" ::: "memory"); \
    __builtin_amdgcn_s_barrier(); \
} while (0)

__global__ __launch_bounds__(256, 2)
void lstm_fused_kernel(const float* __restrict__ x,
                       const float* __restrict__ W_ih,
                       const float* __restrict__ W_hh,
                       const float* __restrict__ b_ih,
                       const float* __restrict__ b_hh,
                       const float* __restrict__ W_fc,
                       const float* __restrict__ b_fc,
                       float* __restrict__ out)
{
    // h double buffer: 16 rows (8 valid, 8..15 stay zero), 64 cols bf16.
    __shared__ short hbuf[2][16][HS];
    __shared__ float Hf[BR][64];

    const int tid  = threadIdx.x;
    const int wave = tid >> 6;
    const int lane = tid & 63;
    const int quad = lane >> 4;
    const int nlow = lane & 15;
    const int jw   = wave * 16 + nlow;   // gate-col this lane's MFMA tiles own
    const int b0   = blockIdx.x * BR;

    // ---- zero h buffers (h0 = 0; rows 8..15 must read as zero forever)
    for (int q = tid; q < 2 * 16 * HS; q += 256) ((short*)hbuf)[q] = (short)0;

    // ---- B fragments (weights) once into registers.
    // lane holds Wcat[col][k = quad*8 + e]; col = g*64 + jw.
    // kt=0: x dims (W_ih); kt=1,2: h dims 0..31 / 32..63 (W_hh).
    short8 bfrag[4][3];
    float  biasg[4];
    for (int g = 0; g < 4; ++g) {
        const int col = g * 64 + jw;
        {
            const float* wr = W_ih + col * I_SZ + quad * 8;
            short8 f;
            #pragma unroll
            for (int e = 0; e < 8; ++e) f[e] = f2bf(wr[e]);
            bfrag[g][0] = f;
        }
        #pragma unroll
        for (int kt = 1; kt < 3; ++kt) {
            const float* wr = W_hh + col * H_SZ + (kt - 1) * 32 + quad * 8;
            short8 f;
            #pragma unroll
            for (int e = 0; e < 8; ++e) f[e] = f2bf(wr[e]);
            bfrag[g][kt] = f;
        }
        biasg[g] = b_ih[col] + b_hh[col];
    }

    // ---- x fragment pointers: lane reads x[b0+nlow][t][quad*8 .. +7].
    // nlow 8..15 read a neighbor block's rows (clamped at the edge) -> their
    // D rows 8..15 are garbage and never consumed.
    const int xrow = min(b0 + nlow, 4096 - 1);
    const float* xb = x + ((size_t)xrow * T_LEN) * I_SZ + quad * 8;

    float4 pa = *(const float4*)(xb + 0);            // x_0
    float4 pb = *(const float4*)(xb + 4);
    float4 qa = *(const float4*)(xb + I_SZ);         // x_1
    float4 qb = *(const float4*)(xb + I_SZ + 4);

    float c[4]  = {0.f, 0.f, 0.f, 0.f};
    float hv[4] = {0.f, 0.f, 0.f, 0.f};

    for (int t = 0; t < T_LEN; ++t) {
        // convert current x_t fragment (off critical path)
        short8 ax;
        ax[0] = f2bf(pa.x); ax[1] = f2bf(pa.y);
        ax[2] = f2bf(pa.z); ax[3] = f2bf(pa.w);
        ax[4] = f2bf(pb.x); ax[5] = f2bf(pb.y);
        ax[6] = f2bf(pb.z); ax[7] = f2bf(pb.w);
        pa = qa; pb = qb;
        if (t + 2 < T_LEN) {                          // prefetch x_{t+2}
            qa = *(const float4*)(xb + (t + 2) * I_SZ);
            qb = *(const float4*)(xb + (t + 2) * I_SZ + 4);
        }

        BAR();                                        // h_{t-1} visible

        // h fragments from LDS: A[m=nlow][k = kt*32 + quad*8 + e]
        const short* hrow = &hbuf[t & 1][nlow][quad * 8];
        short8 a1 = *(const short8*)(hrow);           // h cols 0..31 tile
        short8 a2 = *(const short8*)(hrow + 32);      // h cols 32..63 tile

        f32x4 acc[4];
        #pragma unroll
        for (int g = 0; g < 4; ++g) {
            f32x4 a = {biasg[g], biasg[g], biasg[g], biasg[g]};
            a = __builtin_amdgcn_mfma_f32_16x16x32_bf16(ax, bfrag[g][0], a, 0, 0, 0);
            a = __builtin_amdgcn_mfma_f32_16x16x32_bf16(a1, bfrag[g][1], a, 0, 0, 0);
            a = __builtin_amdgcn_mfma_f32_16x16x32_bf16(a2, bfrag[g][2], a, 0, 0, 0);
            acc[g] = a;
        }

        // D layout: row = quad*4 + q, col = jw. Valid rows 0..7 -> quads 0,1.
        if (quad < 2) {
            #pragma unroll
            for (int q = 0; q < 4; ++q) {
                float iv = sigf(acc[0][q]);
                float fv = sigf(acc[1][q]);
                float gv = tanh_fast(acc[2][q]);
                float ov = sigf(acc[3][q]);
                c[q] = fv * c[q] + iv * gv;
                hv[q] = ov * tanh_fast(c[q]);
                hbuf[(t + 1) & 1][quad * 4 + q][jw] = f2bf(hv[q]);
            }
        }
    }

    // ---- epilogue: out[b0+r][o] = h_T[r] . W_fc[o] + b_fc[o]  (fp32 h)
    if (quad < 2) {
        #pragma unroll
        for (int q = 0; q < 4; ++q) Hf[quad * 4 + q][jw] = hv[q];
    }
    BAR();

    if (tid < BR * O_SZ) {                            // 64 threads
        const int r = tid >> 3;
        const int o = tid & 7;
        const float* wf = W_fc + o * H_SZ;
        float acc = b_fc[o];
        #pragma unroll
        for (int jx = 0; jx < H_SZ; ++jx) acc += Hf[r][jx] * wf[jx];
        out[(size_t)(b0 + r) * O_SZ + o] = acc;
    }
}

extern "C" void kernel_launch(void* const* d_in, const int* in_sizes, int n_in,
                              void* d_out, int out_size, void* d_ws, size_t ws_size,
                              hipStream_t stream) {
    const float* x    = (const float*)d_in[0];
    const float* W_ih = (const float*)d_in[1];
    const float* W_hh = (const float*)d_in[2];
    const float* b_ih = (const float*)d_in[3];
    const float* b_hh = (const float*)d_in[4];
    const float* W_fc = (const float*)d_in[5];
    const float* b_fc = (const float*)d_in[6];
    float* out = (float*)d_out;

    const int B = 4096;
    lstm_fused_kernel<<<dim3(B / BR), dim3(256), 0, stream>>>(
        x, W_ih, W_hh, b_ih, b_hh, W_fc, b_fc, out);
}

// Round 4
// 376.053 us; speedup vs baseline: 1.2413x; 1.2413x over previous
//
#include <hip/hip_runtime.h>
#include <hip/hip_bf16.h>

// LSTM: I=32, H=64, O=8, B=4096, T=256, fused single kernel.
// Round 4: BR=8, grid=512, 2 blocks/CU, __launch_bounds__(256,2).
//  - x fragments loaded straight from global into registers, CHUNKED 8 steps
//    at a time (16x dwordx4 per lane per chunk), so the vmcnt(0) drain that
//    __syncthreads emits hits at most once per 8 steps with ~a full step of
//    work between issue and barrier. Lane reads row b0+(nlow&7): A rows 8..15
//    mirror rows 0..7 (no duplicated HBM fetch, no garbage).
//  - h double-buffered in LDS (8 rows only, mirrored read) -> ONE
//    __syncthreads per step. LDS/step/CU: 16 ds_read_b128 + 32 masked b16
//    writes (~380 cyc, vs ~1400 in round 2).
//  - no gate redistribution: quads 0,1 activate 4 cells each in-register.
//  - bias folded into MFMA acc init.

#define T_LEN 256
#define I_SZ  32
#define H_SZ  64
#define O_SZ  8
#define BR    8
#define HS    72   // h row stride in shorts (36 dwords -> <=2-way banks)

typedef __attribute__((ext_vector_type(8))) short short8;
typedef __attribute__((ext_vector_type(4))) float f32x4;

static __device__ __forceinline__ short f2bf(float f) {
    union { __hip_bfloat16 b; short s; } u;
    u.b = __float2bfloat16(f);
    return u.s;
}
static __device__ __forceinline__ float sigf(float x) {
    return __builtin_amdgcn_rcpf(1.0f + __expf(-x));
}
// tanh(x) = 1 - 2/(1+e^{2x}); saturates correctly via inf/0 at extremes.
static __device__ __forceinline__ float tanh_fast(float x) {
    return 1.0f - 2.0f * __builtin_amdgcn_rcpf(1.0f + __expf(2.0f * x));
}

__global__ __launch_bounds__(256, 2)
void lstm_fused_kernel(const float* __restrict__ x,
                       const float* __restrict__ W_ih,
                       const float* __restrict__ W_hh,
                       const float* __restrict__ b_ih,
                       const float* __restrict__ b_hh,
                       const float* __restrict__ W_fc,
                       const float* __restrict__ b_fc,
                       float* __restrict__ out)
{
    __shared__ short hbuf[2][8][HS];   // h double buffer, bf16, rows 0..7
    __shared__ float Hf[BR][64];

    const int tid  = threadIdx.x;
    const int wave = tid >> 6;
    const int lane = tid & 63;
    const int quad = lane >> 4;
    const int nlow = lane & 15;
    const int row8 = nlow & 7;           // mirrored A-row (8..15 dup 0..7)
    const int jw   = wave * 16 + nlow;   // gate-col this lane's tiles own
    const int b0   = blockIdx.x * BR;

    // ---- B fragments (weights) once into registers.
    // lane holds Wcat[col][k = quad*8 + e]; col = g*64 + jw.
    short8 bfrag[4][3];
    float  biasg[4];
    for (int g = 0; g < 4; ++g) {
        const int col = g * 64 + jw;
        {
            const float* wr = W_ih + col * I_SZ + quad * 8;
            short8 f;
            #pragma unroll
            for (int e = 0; e < 8; ++e) f[e] = f2bf(wr[e]);
            bfrag[g][0] = f;
        }
        #pragma unroll
        for (int kt = 1; kt < 3; ++kt) {
            const float* wr = W_hh + col * H_SZ + (kt - 1) * 32 + quad * 8;
            short8 f;
            #pragma unroll
            for (int e = 0; e < 8; ++e) f[e] = f2bf(wr[e]);
            bfrag[g][kt] = f;
        }
        biasg[g] = b_ih[col] + b_hh[col];
    }

    // ---- zero h buffers (h0 = 0)
    for (int q = tid; q < 2 * 8 * HS; q += 256) ((short*)hbuf)[q] = (short)0;

    // ---- x chunk machinery: lane owns x[b0+row8][t][quad*8 .. +7].
    const float* xb = x + ((size_t)(b0 + row8) * T_LEN) * I_SZ + quad * 8;

    float4 nx[16];                        // next-chunk fp32 (8 steps x 8 floats)
    short8 sc[8];                         // current-chunk bf16 fragments
    #pragma unroll
    for (int s = 0; s < 8; ++s) {
        nx[2*s]   = *(const float4*)(xb + s * I_SZ);
        nx[2*s+1] = *(const float4*)(xb + s * I_SZ + 4);
    }
    #pragma unroll
    for (int s = 0; s < 8; ++s) {
        short8 f;
        f[0] = f2bf(nx[2*s].x);   f[1] = f2bf(nx[2*s].y);
        f[2] = f2bf(nx[2*s].z);   f[3] = f2bf(nx[2*s].w);
        f[4] = f2bf(nx[2*s+1].x); f[5] = f2bf(nx[2*s+1].y);
        f[6] = f2bf(nx[2*s+1].z); f[7] = f2bf(nx[2*s+1].w);
        sc[s] = f;
    }

    float c[4]  = {0.f, 0.f, 0.f, 0.f};
    float hv[4] = {0.f, 0.f, 0.f, 0.f};

    for (int ch = 0; ch < 32; ++ch) {
        #pragma unroll
        for (int tc = 0; tc < 8; ++tc) {
            const int t = ch * 8 + tc;

            __syncthreads();             // h_{t-1} (and, at t=0, zeroing) visible

            // h fragments: A[m][k=32*kt + quad*8 + e], row mirrored
            const short* hr = &hbuf[t & 1][row8][quad * 8];
            short8 a1 = *(const short8*)(hr);        // h cols  0..31 tile
            short8 a2 = *(const short8*)(hr + 32);   // h cols 32..63 tile

            // issue next chunk's global loads early in the chunk
            if (tc == 0 && ch + 1 < 32) {
                const float* nxt = xb + (t + 8) * I_SZ;
                #pragma unroll
                for (int s = 0; s < 8; ++s) {
                    nx[2*s]   = *(const float4*)(nxt + s * I_SZ);
                    nx[2*s+1] = *(const float4*)(nxt + s * I_SZ + 4);
                }
            }

            const short8 ax = sc[tc];

            f32x4 acc[4];
            #pragma unroll
            for (int g = 0; g < 4; ++g) {
                f32x4 a = {biasg[g], biasg[g], biasg[g], biasg[g]};
                a = __builtin_amdgcn_mfma_f32_16x16x32_bf16(ax, bfrag[g][0], a, 0, 0, 0);
                a = __builtin_amdgcn_mfma_f32_16x16x32_bf16(a1, bfrag[g][1], a, 0, 0, 0);
                a = __builtin_amdgcn_mfma_f32_16x16x32_bf16(a2, bfrag[g][2], a, 0, 0, 0);
                acc[g] = a;
            }

            // convert next chunk once its loads have landed (7 steps later)
            if (tc == 7 && ch + 1 < 32) {
                #pragma unroll
                for (int s = 0; s < 8; ++s) {
                    short8 f;
                    f[0] = f2bf(nx[2*s].x);   f[1] = f2bf(nx[2*s].y);
                    f[2] = f2bf(nx[2*s].z);   f[3] = f2bf(nx[2*s].w);
                    f[4] = f2bf(nx[2*s+1].x); f[5] = f2bf(nx[2*s+1].y);
                    f[6] = f2bf(nx[2*s+1].z); f[7] = f2bf(nx[2*s+1].w);
                    sc[s] = f;
                }
            }

            // D layout: row = quad*4 + q, col = jw. Valid rows 0..7 -> quads 0,1.
            if (quad < 2) {
                #pragma unroll
                for (int q = 0; q < 4; ++q) {
                    float iv = sigf(acc[0][q]);
                    float fv = sigf(acc[1][q]);
                    float gv = tanh_fast(acc[2][q]);
                    float ov = sigf(acc[3][q]);
                    c[q] = fv * c[q] + iv * gv;
                    hv[q] = ov * tanh_fast(c[q]);
                    hbuf[(t + 1) & 1][quad * 4 + q][jw] = f2bf(hv[q]);
                }
            }
        }
    }

    // ---- epilogue: out[b0+r][o] = h_T[r] . W_fc[o] + b_fc[o]  (fp32 h)
    if (quad < 2) {
        #pragma unroll
        for (int q = 0; q < 4; ++q) Hf[quad * 4 + q][jw] = hv[q];
    }
    __syncthreads();

    if (tid < BR * O_SZ) {               // 64 threads
        const int r = tid >> 3;
        const int o = tid & 7;
        const float* wf = W_fc + o * H_SZ;
        float acc = b_fc[o];
        #pragma unroll
        for (int jx = 0; jx < H_SZ; ++jx) acc += Hf[r][jx] * wf[jx];
        out[(size_t)(b0 + r) * O_SZ + o] = acc;
    }
}

extern "C" void kernel_launch(void* const* d_in, const int* in_sizes, int n_in,
                              void* d_out, int out_size, void* d_ws, size_t ws_size,
                              hipStream_t stream) {
    const float* x    = (const float*)d_in[0];
    const float* W_ih = (const float*)d_in[1];
    const float* W_hh = (const float*)d_in[2];
    const float* b_ih = (const float*)d_in[3];
    const float* b_hh = (const float*)d_in[4];
    const float* W_fc = (const float*)d_in[5];
    const float* b_fc = (const float*)d_in[6];
    float* out = (float*)d_out;

    const int B = 4096;
    lstm_fused_kernel<<<dim3(B / BR), dim3(256), 0, stream>>>(
        x, W_ih, W_hh, b_ih, b_hh, W_fc, b_fc, out);
}

// Round 5
// 324.541 us; speedup vs baseline: 1.4384x; 1.1587x over previous
//
#include <hip/hip_runtime.h>
#include <hip/hip_bf16.h>

// LSTM: I=32, H=64, O=8, B=4096, T=256, fused single kernel.
// Round 5: BR=8, grid=512, 2 blocks/CU.
// KEY TRICK: A-rows 8..15 mirror rows 0..7, so MFMA D rows 8..15 (held by
// lanes 32..63) are exact duplicates of rows 0..7. Quads 2,3 therefore
// activate rows {2,3}/{6,7} from their OWN accumulators -> dense 2 cells per
// lane, all 64 lanes active, ZERO cross-lane/LDS redistribution.
//  - x fragments from global, chunked 8 steps (vmcnt drain 1x/8 steps).
//  - cheap bf16 convert: (bits+0x8000)>>16, packed pairwise via v_perm_b32.
//  - h double-buffered in LDS, ONE __syncthreads per step.
//  - bias folded into MFMA acc init.

#define T_LEN 256
#define I_SZ  32
#define H_SZ  64
#define O_SZ  8
#define BR    8
#define HS    72   // h row stride in shorts

typedef __attribute__((ext_vector_type(8))) short short8;
typedef __attribute__((ext_vector_type(4))) float f32x4;

union U4S8 { uint4 u; short8 s; };

static __device__ __forceinline__ unsigned fbits(float f) {
    union { float f; unsigned u; } v; v.f = f; return v.u;
}
// round-to-nearest (half-up) bf16, low 16 bits of result
static __device__ __forceinline__ unsigned bfr(float f) {
    return (fbits(f) + 0x8000u) >> 16;
}
// two floats -> packed bf16x2 in one dword: {hi16(b+r), hi16(a+r)}
static __device__ __forceinline__ unsigned pk2(float lo, float hi) {
    unsigned a = fbits(lo) + 0x8000u;
    unsigned b = fbits(hi) + 0x8000u;
    return __builtin_amdgcn_perm(b, a, 0x07060302u);
}
static __device__ __forceinline__ short f2bf_rne(float f) {   // init-time only
    union { __hip_bfloat16 b; short s; } u;
    u.b = __float2bfloat16(f);
    return u.s;
}
static __device__ __forceinline__ float sigf(float x) {
    return __builtin_amdgcn_rcpf(1.0f + __expf(-x));
}
// tanh(x) = 1 - 2/(1+e^{2x}); saturates correctly via inf/0 at extremes.
static __device__ __forceinline__ float tanh_fast(float x) {
    return 1.0f - 2.0f * __builtin_amdgcn_rcpf(1.0f + __expf(2.0f * x));
}

__global__ __launch_bounds__(256, 2)
void lstm_fused_kernel(const float* __restrict__ x,
                       const float* __restrict__ W_ih,
                       const float* __restrict__ W_hh,
                       const float* __restrict__ b_ih,
                       const float* __restrict__ b_hh,
                       const float* __restrict__ W_fc,
                       const float* __restrict__ b_fc,
                       float* __restrict__ out)
{
    __shared__ short hbuf[2][8][HS];   // h double buffer, bf16, rows 0..7
    __shared__ float Hf[BR][64];

    const int tid  = threadIdx.x;
    const int wave = tid >> 6;
    const int lane = tid & 63;
    const int quad = lane >> 4;
    const int nlow = lane & 15;
    const int row8 = nlow & 7;           // mirrored A-row (8..15 dup 0..7)
    const int jw   = wave * 16 + nlow;   // gate-col this lane's tiles own
    const int b0   = blockIdx.x * BR;

    // rows this lane activates: ra, ra+1
    const int ra    = (quad & 1) * 4 + (quad >> 1) * 2;
    const bool upper = (quad & 2) != 0;  // use acc[2],[3] instead of [0],[1]

    // ---- B fragments (weights) once into registers.
    short8 bfrag[4][3];
    float  biasg[4];
    for (int g = 0; g < 4; ++g) {
        const int col = g * 64 + jw;
        {
            const float* wr = W_ih + col * I_SZ + quad * 8;
            short8 f;
            #pragma unroll
            for (int e = 0; e < 8; ++e) f[e] = f2bf_rne(wr[e]);
            bfrag[g][0] = f;
        }
        #pragma unroll
        for (int kt = 1; kt < 3; ++kt) {
            const float* wr = W_hh + col * H_SZ + (kt - 1) * 32 + quad * 8;
            short8 f;
            #pragma unroll
            for (int e = 0; e < 8; ++e) f[e] = f2bf_rne(wr[e]);
            bfrag[g][kt] = f;
        }
        biasg[g] = b_ih[col] + b_hh[col];
    }

    // ---- zero h buffers (h0 = 0)
    for (int q = tid; q < 2 * 8 * HS; q += 256) ((short*)hbuf)[q] = (short)0;

    // ---- x chunk machinery: lane owns x[b0+row8][t][quad*8 .. +7].
    const float* xb = x + ((size_t)(b0 + row8) * T_LEN) * I_SZ + quad * 8;

    float4 nx[16];                        // next-chunk fp32 (8 steps x 8 floats)
    short8 sc[8];                         // current-chunk bf16 fragments
    #pragma unroll
    for (int s = 0; s < 8; ++s) {
        nx[2*s]   = *(const float4*)(xb + s * I_SZ);
        nx[2*s+1] = *(const float4*)(xb + s * I_SZ + 4);
    }
    #pragma unroll
    for (int s = 0; s < 8; ++s) {
        U4S8 v;
        v.u.x = pk2(nx[2*s].x,   nx[2*s].y);
        v.u.y = pk2(nx[2*s].z,   nx[2*s].w);
        v.u.z = pk2(nx[2*s+1].x, nx[2*s+1].y);
        v.u.w = pk2(nx[2*s+1].z, nx[2*s+1].w);
        sc[s] = v.s;
    }

    // LDS addresses (buffer-alternation folded at compile time in the
    // unrolled tc loop)
    const short* rb[2] = { &hbuf[0][row8][quad * 8], &hbuf[1][row8][quad * 8] };
    short*       wb[2] = { &hbuf[0][ra][jw],         &hbuf[1][ra][jw] };

    float c0 = 0.f, c1 = 0.f, hv0 = 0.f, hv1 = 0.f;

    for (int ch = 0; ch < 32; ++ch) {
        #pragma unroll
        for (int tc = 0; tc < 8; ++tc) {
            const int t = ch * 8 + tc;

            __syncthreads();             // h_{t-1} (and at t=0 the zeroing) visible

            // h fragments: A[m=row][k = 32*kt + quad*8 + e], row mirrored
            const short* hr = rb[t & 1];
            short8 a1 = *(const short8*)(hr);        // h cols  0..31
            short8 a2 = *(const short8*)(hr + 32);   // h cols 32..63

            // issue next chunk's global loads early in the chunk
            if (tc == 0 && ch + 1 < 32) {
                const float* nxt = xb + (t + 8) * I_SZ;
                #pragma unroll
                for (int s = 0; s < 8; ++s) {
                    nx[2*s]   = *(const float4*)(nxt + s * I_SZ);
                    nx[2*s+1] = *(const float4*)(nxt + s * I_SZ + 4);
                }
            }

            const short8 ax = sc[tc];

            f32x4 acc[4];
            #pragma unroll
            for (int g = 0; g < 4; ++g) {
                f32x4 a = {biasg[g], biasg[g], biasg[g], biasg[g]};
                a = __builtin_amdgcn_mfma_f32_16x16x32_bf16(ax, bfrag[g][0], a, 0, 0, 0);
                a = __builtin_amdgcn_mfma_f32_16x16x32_bf16(a1, bfrag[g][1], a, 0, 0, 0);
                a = __builtin_amdgcn_mfma_f32_16x16x32_bf16(a2, bfrag[g][2], a, 0, 0, 0);
                acc[g] = a;
            }

            // convert next chunk once its loads landed (7 steps of cover)
            if (tc == 7 && ch + 1 < 32) {
                #pragma unroll
                for (int s = 0; s < 8; ++s) {
                    U4S8 v;
                    v.u.x = pk2(nx[2*s].x,   nx[2*s].y);
                    v.u.y = pk2(nx[2*s].z,   nx[2*s].w);
                    v.u.z = pk2(nx[2*s+1].x, nx[2*s+1].y);
                    v.u.w = pk2(nx[2*s+1].z, nx[2*s+1].w);
                    sc[s] = v.s;
                }
            }

            // ---- dense cell update: 2 cells/lane, all 64 lanes active.
            // D rows 8..15 duplicate rows 0..7, so quads 2,3 use acc[2],[3]
            // (their own registers) for rows ra=2,3 / 6,7.
            float p0[4], p1[4];
            #pragma unroll
            for (int g = 0; g < 4; ++g) {
                p0[g] = upper ? acc[g][2] : acc[g][0];
                p1[g] = upper ? acc[g][3] : acc[g][1];
            }
            short* hw = wb[(t + 1) & 1];
            {
                float iv = sigf(p0[0]), fv = sigf(p0[1]);
                float gv = tanh_fast(p0[2]), ov = sigf(p0[3]);
                c0 = fv * c0 + iv * gv;
                hv0 = ov * tanh_fast(c0);
                hw[0] = (short)bfr(hv0);
            }
            {
                float iv = sigf(p1[0]), fv = sigf(p1[1]);
                float gv = tanh_fast(p1[2]), ov = sigf(p1[3]);
                c1 = fv * c1 + iv * gv;
                hv1 = ov * tanh_fast(c1);
                hw[HS] = (short)bfr(hv1);
            }
        }
    }

    // ---- epilogue: out[b0+r][o] = h_T[r] . W_fc[o] + b_fc[o]  (fp32 h)
    Hf[ra][jw]     = hv0;
    Hf[ra + 1][jw] = hv1;
    __syncthreads();

    if (tid < BR * O_SZ) {               // 64 threads
        const int r = tid >> 3;
        const int o = tid & 7;
        const float* wf = W_fc + o * H_SZ;
        float acc = b_fc[o];
        #pragma unroll
        for (int jx = 0; jx < H_SZ; ++jx) acc += Hf[r][jx] * wf[jx];
        out[(size_t)(b0 + r) * O_SZ + o] = acc;
    }
}

extern "C" void kernel_launch(void* const* d_in, const int* in_sizes, int n_in,
                              void* d_out, int out_size, void* d_ws, size_t ws_size,
                              hipStream_t stream) {
    const float* x    = (const float*)d_in[0];
    const float* W_ih = (const float*)d_in[1];
    const float* W_hh = (const float*)d_in[2];
    const float* b_ih = (const float*)d_in[3];
    const float* b_hh = (const float*)d_in[4];
    const float* W_fc = (const float*)d_in[5];
    const float* b_fc = (const float*)d_in[6];
    float* out = (float*)d_out;

    const int B = 4096;
    lstm_fused_kernel<<<dim3(B / BR), dim3(256), 0, stream>>>(
        x, W_ih, W_hh, b_ih, b_hh, W_fc, b_fc, out);
}

// Round 6
// 318.395 us; speedup vs baseline: 1.4661x; 1.0193x over previous
//
#include <hip/hip_runtime.h>
#include <hip/hip_bf16.h>

// LSTM: I=32, H=64, O=8, B=4096, T=256, fused single kernel.
// Round 6: BR=8, grid=512, 2 blocks/CU. Attack = transcendental issue cost.
//  - Activations via Pade[5/4] rationals (NO exp): 1 v_rcp + ~8 FMA per
//    activation instead of exp+rcp. Denominators >= 945: rcp always safe.
//  - Both cells of a lane packed as float2 -> v_pk_fma_f32 etc.
//  - Permuted mirror-read f(nlow) = {0..7,2,3,2,3,6,7,6,7}: D rows 8,9/12,13
//    hold cells 2,3/6,7 -> every lane uses acc[0..1]; no cndmask selects,
//    cell pair = {acc[g][0],acc[g][1]} directly.
//  - Bias as live f32x4 C-operand (no per-step acc-init movs).
//  - x from global, chunked 8 steps; bf16 truncation pack (1 v_perm / pair).
//  - h double-buffered in LDS, ONE __syncthreads per step.

#define T_LEN 256
#define I_SZ  32
#define H_SZ  64
#define O_SZ  8
#define BR    8
#define HS    72   // h row stride in shorts

typedef __attribute__((ext_vector_type(8))) short short8;
typedef __attribute__((ext_vector_type(4))) float f32x4;
typedef __attribute__((ext_vector_type(2))) float f32x2;

static __device__ __forceinline__ unsigned fbits(float f) {
    union { float f; unsigned u; } v; v.f = f; return v.u;
}
// two floats -> packed bf16x2 (truncation): elem0 = lo, elem1 = hi
static __device__ __forceinline__ unsigned pk2t(float lo, float hi) {
    return __builtin_amdgcn_perm(fbits(hi), fbits(lo), 0x07060302u);
}
static __device__ __forceinline__ short f2bf_rne(float f) {   // init-time only
    union { __hip_bfloat16 b; short s; } u;
    u.b = __float2bfloat16(f);
    return u.s;
}
static __device__ __forceinline__ f32x2 rcp2(f32x2 d) {
    f32x2 r;
    r.x = __builtin_amdgcn_rcpf(d.x);
    r.y = __builtin_amdgcn_rcpf(d.y);
    return r;
}
static __device__ __forceinline__ f32x2 fma2(f32x2 a, f32x2 b, f32x2 c) {
    return __builtin_elementwise_fma(a, b, c);
}
// tanh Pade[5/4], clamped. |err| <~ 1.1e-3, den >= 945.
static __device__ __forceinline__ f32x2 tanh2(f32x2 x) {
    f32x2 x2 = x * x;
    f32x2 n  = fma2(x2 + 105.0f, x2, (f32x2)(945.0f));
    f32x2 d  = fma2(fma2((f32x2)(15.0f), x2, (f32x2)(420.0f)), x2, (f32x2)(945.0f));
    f32x2 r  = (x * n) * rcp2(d);
    r = __builtin_elementwise_min(r, (f32x2)(1.0f));
    r = __builtin_elementwise_max(r, (f32x2)(-1.0f));
    return r;
}
// sigmoid = 0.5 + 0.5*tanh(x/2) via folded Pade. |err| <~ 5.5e-4, den >= 60480.
static __device__ __forceinline__ f32x2 sig2(f32x2 x) {
    f32x2 x2 = x * x;
    f32x2 n  = fma2(x2 + 420.0f, x2, (f32x2)(15120.0f));
    f32x2 d  = fma2(fma2((f32x2)(60.0f), x2, (f32x2)(6720.0f)), x2, (f32x2)(60480.0f));
    f32x2 r  = fma2(x * n, rcp2(d), (f32x2)(0.5f));
    r = __builtin_elementwise_min(r, (f32x2)(1.0f));
    r = __builtin_elementwise_max(r, (f32x2)(0.0f));
    return r;
}

__global__ __launch_bounds__(256, 2)
void lstm_fused_kernel(const float* __restrict__ x,
                       const float* __restrict__ W_ih,
                       const float* __restrict__ W_hh,
                       const float* __restrict__ b_ih,
                       const float* __restrict__ b_hh,
                       const float* __restrict__ W_fc,
                       const float* __restrict__ b_fc,
                       float* __restrict__ out)
{
    __shared__ short hbuf[2][8][HS];   // h double buffer, bf16, rows 0..7
    __shared__ float Hf[BR][64];

    const int tid  = threadIdx.x;
    const int wave = tid >> 6;
    const int lane = tid & 63;
    const int quad = lane >> 4;
    const int nlow = lane & 15;
    const int jw   = wave * 16 + nlow;   // gate-col this lane's tiles own
    const int b0   = blockIdx.x * BR;

    // Permuted mirror row for A-reads: {0..7, 2,3,2,3, 6,7,6,7}
    const int fr = (nlow < 8) ? nlow : (((nlow & 4) ? 6 : 2) + (nlow & 1));
    // Cell rows this lane owns (uses acc[0],acc[1]): q0->0,1 q1->4,5 q2->2,3 q3->6,7
    const int ra = ((quad & 1) << 2) | (quad & 2);

    // ---- B fragments (weights) once into registers.
    short8 bfrag[4][3];
    f32x4  biasf[4];
    for (int g = 0; g < 4; ++g) {
        const int col = g * 64 + jw;
        {
            const float* wr = W_ih + col * I_SZ + quad * 8;
            short8 f;
            #pragma unroll
            for (int e = 0; e < 8; ++e) f[e] = f2bf_rne(wr[e]);
            bfrag[g][0] = f;
        }
        #pragma unroll
        for (int kt = 1; kt < 3; ++kt) {
            const float* wr = W_hh + col * H_SZ + (kt - 1) * 32 + quad * 8;
            short8 f;
            #pragma unroll
            for (int e = 0; e < 8; ++e) f[e] = f2bf_rne(wr[e]);
            bfrag[g][kt] = f;
        }
        const float bg = b_ih[col] + b_hh[col];
        biasf[g] = (f32x4){bg, bg, bg, bg};
    }

    // ---- zero h buffers (h0 = 0)
    for (int q = tid; q < 2 * 8 * HS; q += 256) ((short*)hbuf)[q] = (short)0;

    // ---- x chunk machinery: lane owns x[b0+fr][t][quad*8 .. +7].
    const float* xb = x + ((size_t)(b0 + fr) * T_LEN) * I_SZ + quad * 8;

    float4 nx[16];                        // next-chunk fp32 (8 steps x 8 floats)
    short8 sc[8];                         // current-chunk bf16 fragments
    #pragma unroll
    for (int s = 0; s < 8; ++s) {
        nx[2*s]   = *(const float4*)(xb + s * I_SZ);
        nx[2*s+1] = *(const float4*)(xb + s * I_SZ + 4);
    }
    #pragma unroll
    for (int s = 0; s < 8; ++s) {
        union { uint4 u; short8 v; } w;
        w.u.x = pk2t(nx[2*s].x,   nx[2*s].y);
        w.u.y = pk2t(nx[2*s].z,   nx[2*s].w);
        w.u.z = pk2t(nx[2*s+1].x, nx[2*s+1].y);
        w.u.w = pk2t(nx[2*s+1].z, nx[2*s+1].w);
        sc[s] = w.v;
    }

    // LDS addresses
    const short* rb[2] = { &hbuf[0][fr][quad * 8], &hbuf[1][fr][quad * 8] };
    short*       wb[2] = { &hbuf[0][ra][jw],       &hbuf[1][ra][jw] };

    f32x2 cc = {0.f, 0.f};
    f32x2 hh = {0.f, 0.f};

    for (int ch = 0; ch < 32; ++ch) {
        #pragma unroll
        for (int tc = 0; tc < 8; ++tc) {
            const int t = ch * 8 + tc;

            __syncthreads();             // h_{t-1} (and at t=0 the zeroing) visible

            // h fragments: A[m][k = 32*kt + quad*8 + e], rows via fr
            const short* hr = rb[t & 1];
            short8 a1 = *(const short8*)(hr);        // h cols  0..31
            short8 a2 = *(const short8*)(hr + 32);   // h cols 32..63

            // issue next chunk's global loads early in the chunk
            if (tc == 0 && ch + 1 < 32) {
                const float* nxt = xb + (t + 8) * I_SZ;
                #pragma unroll
                for (int s = 0; s < 8; ++s) {
                    nx[2*s]   = *(const float4*)(nxt + s * I_SZ);
                    nx[2*s+1] = *(const float4*)(nxt + s * I_SZ + 4);
                }
            }

            const short8 ax = sc[tc];

            f32x4 acc[4];
            #pragma unroll
            for (int g = 0; g < 4; ++g) {
                f32x4 a = __builtin_amdgcn_mfma_f32_16x16x32_bf16(ax, bfrag[g][0], biasf[g], 0, 0, 0);
                a = __builtin_amdgcn_mfma_f32_16x16x32_bf16(a1, bfrag[g][1], a, 0, 0, 0);
                a = __builtin_amdgcn_mfma_f32_16x16x32_bf16(a2, bfrag[g][2], a, 0, 0, 0);
                acc[g] = a;
            }

            // convert next chunk once its loads landed (7 steps of cover)
            if (tc == 7 && ch + 1 < 32) {
                #pragma unroll
                for (int s = 0; s < 8; ++s) {
                    union { uint4 u; short8 v; } w;
                    w.u.x = pk2t(nx[2*s].x,   nx[2*s].y);
                    w.u.y = pk2t(nx[2*s].z,   nx[2*s].w);
                    w.u.z = pk2t(nx[2*s+1].x, nx[2*s+1].y);
                    w.u.w = pk2t(nx[2*s+1].z, nx[2*s+1].w);
                    sc[s] = w.v;
                }
            }

            // ---- dense packed cell update: cells (ra, jw) and (ra+1, jw).
            // Every lane uses acc[g][0..1] thanks to the permuted mirror read.
            f32x2 pI = {acc[0][0], acc[0][1]};
            f32x2 pF = {acc[1][0], acc[1][1]};
            f32x2 pG = {acc[2][0], acc[2][1]};
            f32x2 pO = {acc[3][0], acc[3][1]};

            f32x2 iv = sig2(pI);
            f32x2 fv = sig2(pF);
            f32x2 gv = tanh2(pG);
            f32x2 ov = sig2(pO);
            cc = fma2(fv, cc, iv * gv);
            hh = ov * tanh2(cc);

            short* hw = wb[(t + 1) & 1];
            hw[0]  = (short)((fbits(hh.x) + 0x8000u) >> 16);
            hw[HS] = (short)((fbits(hh.y) + 0x8000u) >> 16);
        }
    }

    // ---- epilogue: out[b0+r][o] = h_T[r] . W_fc[o] + b_fc[o]  (fp32 h)
    Hf[ra][jw]     = hh.x;
    Hf[ra + 1][jw] = hh.y;
    __syncthreads();

    if (tid < BR * O_SZ) {               // 64 threads
        const int r = tid >> 3;
        const int o = tid & 7;
        const float* wf = W_fc + o * H_SZ;
        float acc = b_fc[o];
        #pragma unroll
        for (int jx = 0; jx < H_SZ; ++jx) acc += Hf[r][jx] * wf[jx];
        out[(size_t)(b0 + r) * O_SZ + o] = acc;
    }
}

extern "C" void kernel_launch(void* const* d_in, const int* in_sizes, int n_in,
                              void* d_out, int out_size, void* d_ws, size_t ws_size,
                              hipStream_t stream) {
    const float* x    = (const float*)d_in[0];
    const float* W_ih = (const float*)d_in[1];
    const float* W_hh = (const float*)d_in[2];
    const float* b_ih = (const float*)d_in[3];
    const float* b_hh = (const float*)d_in[4];
    const float* W_fc = (const float*)d_in[5];
    const float* b_fc = (const float*)d_in[6];
    float* out = (float*)d_out;

    const int B = 4096;
    lstm_fused_kernel<<<dim3(B / BR), dim3(256), 0, stream>>>(
        x, W_ih, W_hh, b_ih, b_hh, W_fc, b_fc, out);
}